// Round 16
// baseline (258.287 us; speedup 1.0000x reference)
//
#include <hip/hip_runtime.h>
#include <hip/hip_bf16.h>
#include <cstdint>
#include <cstddef>
#include <type_traits>

#define SLOPE 0.2f

typedef __attribute__((ext_vector_type(8))) short short8v;
typedef __attribute__((ext_vector_type(4))) float float4v;

__device__ inline ushort f2bf(float f) {
  uint u = __float_as_uint(f);
  uint r = (u + 0x7FFFu + ((u >> 16) & 1u)) >> 16;
  return (ushort)r;
}
__device__ inline float bf2f(ushort u) {
  return __uint_as_float(((uint)u) << 16);
}
__device__ inline float bflo(uint u) { return __uint_as_float(u << 16); }
__device__ inline float bfhi(uint u) { return __uint_as_float(u & 0xffff0000u); }

__device__ inline short8v pack8(float4 a, float4 b) {
  uint4 r;
  r.x = (uint)f2bf(a.x) | ((uint)f2bf(a.y) << 16);
  r.y = (uint)f2bf(a.z) | ((uint)f2bf(a.w) << 16);
  r.z = (uint)f2bf(b.x) | ((uint)f2bf(b.y) << 16);
  r.w = (uint)f2bf(b.z) | ((uint)f2bf(b.w) << 16);
  return __builtin_bit_cast(short8v, r);
}
__device__ inline float lrelu(float v) { return (v > 0.f) ? v : SLOPE * v; }

// ---------------- init: zero counts + convert W0/W1 to bf16 (one kernel) ----

__global__ void k_init(const float* __restrict__ W0, const float* __restrict__ W1,
                       ushort* __restrict__ Wb0, ushort* __restrict__ Wb1,
                       int4* __restrict__ counts4, int n4) {
  int i = blockIdx.x * 256 + threadIdx.x;
  if (i < 128 * 256) Wb0[i] = f2bf(W0[i]);
  if (i < 128 * 128) Wb1[i] = f2bf(W1[i]);
  if (i < n4) counts4[i] = make_int4(0, 0, 0, 0);
}

// ---------------- CSR build ----------------

__global__ void k_count(const int* __restrict__ dst, int* __restrict__ counts, int E) {
  int e = blockIdx.x * 256 + threadIdx.x;
  if (e < E) atomicAdd(&counts[dst[e]], 1);
}

__global__ void k_scan1(const int* __restrict__ counts, int* __restrict__ excl,
                        int* __restrict__ bsums, int N) {
  __shared__ int lds[256];
  int tid = threadIdx.x;
  int base = blockIdx.x * 2048 + tid * 8;
  int v[8];
  int ts = 0;
#pragma unroll
  for (int i = 0; i < 8; i++) {
    int idx = base + i;
    int t = (idx < N) ? counts[idx] : 0;
    v[i] = ts;
    ts += t;
  }
  lds[tid] = ts;
  __syncthreads();
  for (int off = 1; off < 256; off <<= 1) {
    int t = (tid >= off) ? lds[tid - off] : 0;
    __syncthreads();
    lds[tid] += t;
    __syncthreads();
  }
  int texcl = (tid > 0) ? lds[tid - 1] : 0;
#pragma unroll
  for (int i = 0; i < 8; i++) {
    int idx = base + i;
    if (idx < N) excl[idx] = texcl + v[i];
  }
  if (tid == 255) bsums[blockIdx.x] = lds[255];
}

// scan finish: each block sums the preceding block-sums itself (nb <= 49)
__global__ void k_scan23(int* __restrict__ excl, int* __restrict__ cursor,
                         const int* __restrict__ bsums, int N) {
  int off = 0;
  for (int j = 0; j < blockIdx.x; j++) off += bsums[j];
  int tid = threadIdx.x;
  int base = blockIdx.x * 2048 + tid * 8;
#pragma unroll
  for (int i = 0; i < 8; i++) {
    int idx = base + i;
    if (idx < N) {
      int val = excl[idx] + off;
      excl[idx] = val;
      cursor[idx] = val;
    }
  }
}

__global__ void k_fill(const int* __restrict__ src, const int* __restrict__ dst,
                       int* __restrict__ cursor,
                       int* __restrict__ src_sorted, int* __restrict__ dst_sorted,
                       int E) {
  int e = blockIdx.x * 256 + threadIdx.x;
  if (e < E) {
    int d = dst[e];
    int pos = atomicAdd(&cursor[d], 1);
    src_sorted[pos] = src[e];
    dst_sorted[pos] = d;
  }
}

// ---------------- MFMA GEMM: 64-row tiles, W in LDS, batched A-loads --------

template <typename AT, int K>
__global__ __launch_bounds__(256, 4) void k_gemm_lds(
    const AT* __restrict__ A, const ushort* __restrict__ Wb,
    const float* __restrict__ att_src, const float* __restrict__ att_dst,
    ushort* __restrict__ C, float* __restrict__ a_src, float* __restrict__ a_dst,
    int M) {
  constexpr int KH = 128;              // staged K chunk
  constexpr int LDW = KH + 8;
  __shared__ ushort Ws[128 * LDW];     // 34816 B
  const int tid = threadIdx.x;
  const int wave = tid >> 6, lane = tid & 63;
  const int fr = lane & 15, fq = lane >> 4;
  const int bm = blockIdx.x * 64;
  const int r0 = bm + wave * 16 + fr;
  const int rc0 = min(r0, M - 1);
  const AT* arow = A + (size_t)rc0 * K + fq * 8;

  const int sr = tid >> 1;                  // staging row 0..127
  const int scb = (tid & 1) * (KH / 2);     // staging col base {0,64}
  const ushort* wrow = Wb + (size_t)sr * K + scb;
  ushort* drow = &Ws[sr * LDW + scb];

  // stage W half 0 (ds_writes issued; barrier comes after A-load issue)
#pragma unroll
  for (int i = 0; i < KH / 16; i++)
    *(uint4*)(drow + i * 8) = *(const uint4*)(wrow + i * 8);

  float4v acc[8] = {};

  if constexpr (std::is_same<AT, float>::value) {
    // ---- fp32 A (layer 0, K=256) ----
    float4 a0[4][2];
#pragma unroll
    for (int s = 0; s < 4; s++) {              // 8 loads in flight
      const float* p = arow + s * 32;
      a0[s][0] = *(const float4*)p;
      a0[s][1] = *(const float4*)(p + 4);
    }
    __syncthreads();                           // W0 staged; A0 still flying
#pragma unroll
    for (int s = 0; s < 4; s++) {
      short8v af = pack8(a0[s][0], a0[s][1]);
#pragma unroll
      for (int t = 0; t < 8; t++) {
        short8v bfr = *(const short8v*)&Ws[(t * 16 + fr) * LDW + s * 32 + fq * 8];
        acc[t] = __builtin_amdgcn_mfma_f32_16x16x32_bf16(af, bfr, acc[t], 0, 0, 0);
      }
    }
    // half 1: issue A loads BEFORE the restage barriers
    float4 a1[4][2];
#pragma unroll
    for (int s = 0; s < 4; s++) {
      const float* p = arow + KH + s * 32;
      a1[s][0] = *(const float4*)p;
      a1[s][1] = *(const float4*)(p + 4);
    }
    __syncthreads();                           // all waves done reading W0
#pragma unroll
    for (int i = 0; i < KH / 16; i++)
      *(uint4*)(drow + i * 8) = *(const uint4*)(wrow + KH + i * 8);
    __syncthreads();                           // W1 staged; A1 long in flight
#pragma unroll
    for (int s = 0; s < 4; s++) {
      short8v af = pack8(a1[s][0], a1[s][1]);
#pragma unroll
      for (int t = 0; t < 8; t++) {
        short8v bfr = *(const short8v*)&Ws[(t * 16 + fr) * LDW + s * 32 + fq * 8];
        acc[t] = __builtin_amdgcn_mfma_f32_16x16x32_bf16(af, bfr, acc[t], 0, 0, 0);
      }
    }
  } else {
    // ---- bf16 A (layer 1, K=128) ----
    short8v a0[4];
#pragma unroll
    for (int s = 0; s < 4; s++)                // 4 loads in flight
      a0[s] = *(const short8v*)(arow + s * 32);
    __syncthreads();
#pragma unroll
    for (int s = 0; s < 4; s++) {
#pragma unroll
      for (int t = 0; t < 8; t++) {
        short8v bfr = *(const short8v*)&Ws[(t * 16 + fr) * LDW + s * 32 + fq * 8];
        acc[t] = __builtin_amdgcn_mfma_f32_16x16x32_bf16(a0[s], bfr, acc[t], 0, 0, 0);
      }
    }
  }

  // att coefficients for this lane's columns (t*16+fr)
  float asc[8], adc[8];
#pragma unroll
  for (int t = 0; t < 8; t++) {
    asc[t] = att_src[t * 16 + fr];
    adc[t] = att_dst[t * 16 + fr];
  }

#pragma unroll
  for (int j = 0; j < 4; j++) {
    int row = bm + wave * 16 + fq * 4 + j;
    bool ok = row < M;
    if (ok) {
#pragma unroll
      for (int t = 0; t < 8; t++)
        C[(size_t)row * 128 + t * 16 + fr] = f2bf(acc[t][j]);
    }
    float ps[4], pd[4];
#pragma unroll
    for (int h = 0; h < 4; h++) {
      ps[h] = acc[2 * h][j] * asc[2 * h] + acc[2 * h + 1][j] * asc[2 * h + 1];
      pd[h] = acc[2 * h][j] * adc[2 * h] + acc[2 * h + 1][j] * adc[2 * h + 1];
    }
#pragma unroll
    for (int off = 1; off < 16; off <<= 1) {
#pragma unroll
      for (int h = 0; h < 4; h++) {
        ps[h] += __shfl_xor(ps[h], off);
        pd[h] += __shfl_xor(pd[h], off);
      }
    }
    if (ok && fr == 0) {
      *(float4*)&a_src[(size_t)row * 4] = make_float4(ps[0], ps[1], ps[2], ps[3]);
      *(float4*)&a_dst[(size_t)row * 4] = make_float4(pd[0], pd[1], pd[2], pd[3]);
    }
  }
}

// ---------------- edge weights: w[pos][h] = exp(lrelu(a_src[s]+a_dst[d])) ---
// Edge-parallel, fully coalesced; a_src/a_dst are L2-resident (1.6 MB each).
// Hoists the exp + random a_src gather out of k_agg (was recomputed 32x/edge).

__global__ void k_wedge(const int* __restrict__ ssort, const int* __restrict__ dsort,
                        const float* __restrict__ a_src, const float* __restrict__ a_dst,
                        float* __restrict__ w, int E) {
  int p = blockIdx.x * 256 + threadIdx.x;
  if (p >= E) return;
  int s = ssort[p], d = dsort[p];
  float4 as4 = *(const float4*)&a_src[(size_t)s * 4];
  float4 ad4 = *(const float4*)&a_dst[(size_t)d * 4];
  float4 wv;
  wv.x = __expf(lrelu(as4.x + ad4.x));
  wv.y = __expf(lrelu(as4.y + ad4.y));
  wv.z = __expf(lrelu(as4.z + ad4.z));
  wv.w = __expf(lrelu(as4.w + ad4.w));
  *(float4*)&w[(size_t)p * 4] = wv;
}

// ---------------- single-pass aggregation: 32 thr/node, unroll x4 ----------
// Weights read sequentially from w_sorted (one 16B line/edge, lane-broadcast);
// no exp, no a_src gather in the hot loop. No max-subtraction (logits
// bounded; exp ratio identical).

template <bool RELU, typename OT>
__global__ __launch_bounds__(256) void k_agg(const ushort* __restrict__ xp,
                                             const float* __restrict__ wbuf,
                                             const int* __restrict__ src_sorted,
                                             const int* __restrict__ indptr,
                                             const int* __restrict__ counts,
                                             const float* __restrict__ bias,
                                             OT* __restrict__ out, int N) {
  int tid = threadIdx.x;
  int n = blockIdx.x * 8 + (tid >> 5);
  if (n >= N) return;
  int c4 = tid & 31;          // channel group: channels 4*c4 .. 4*c4+3
  int h = c4 >> 3;
  int deg = counts[n];
  int start = indptr[n];
  const int* sp = src_sorted + start;
  const float* wp = wbuf + (size_t)start * 4 + h;
  const ushort* xpc = xp + c4 * 4;

  float a0 = 0.f, a1 = 0.f, a2 = 0.f, a3 = 0.f, s = 0.f;
  int i = 0;
  for (; i + 4 <= deg; i += 4) {
    int s0 = sp[i], s1 = sp[i + 1], s2 = sp[i + 2], s3 = sp[i + 3];
    float x0 = wp[(i + 0) * 4], x1 = wp[(i + 1) * 4];
    float x2 = wp[(i + 2) * 4], x3 = wp[(i + 3) * 4];
    uint2 v0 = *(const uint2*)(xpc + (size_t)s0 * 128);
    uint2 v1 = *(const uint2*)(xpc + (size_t)s1 * 128);
    uint2 v2 = *(const uint2*)(xpc + (size_t)s2 * 128);
    uint2 v3 = *(const uint2*)(xpc + (size_t)s3 * 128);
    s += x0 + x1 + x2 + x3;
    a0 = fmaf(bflo(v0.x), x0, a0); a1 = fmaf(bfhi(v0.x), x0, a1);
    a2 = fmaf(bflo(v0.y), x0, a2); a3 = fmaf(bfhi(v0.y), x0, a3);
    a0 = fmaf(bflo(v1.x), x1, a0); a1 = fmaf(bfhi(v1.x), x1, a1);
    a2 = fmaf(bflo(v1.y), x1, a2); a3 = fmaf(bfhi(v1.y), x1, a3);
    a0 = fmaf(bflo(v2.x), x2, a0); a1 = fmaf(bfhi(v2.x), x2, a1);
    a2 = fmaf(bflo(v2.y), x2, a2); a3 = fmaf(bfhi(v2.y), x2, a3);
    a0 = fmaf(bflo(v3.x), x3, a0); a1 = fmaf(bfhi(v3.x), x3, a1);
    a2 = fmaf(bflo(v3.y), x3, a2); a3 = fmaf(bfhi(v3.y), x3, a3);
  }
  for (; i < deg; i++) {
    int s0 = sp[i];
    float x0 = wp[i * 4];
    uint2 v0 = *(const uint2*)(xpc + (size_t)s0 * 128);
    s += x0;
    a0 = fmaf(bflo(v0.x), x0, a0); a1 = fmaf(bfhi(v0.x), x0, a1);
    a2 = fmaf(bflo(v0.y), x0, a2); a3 = fmaf(bfhi(v0.y), x0, a3);
  }

  float inv = 1.f / (s + 1e-16f);
  float4 bv = *(const float4*)&bias[c4 * 4];
  float o0 = fmaf(a0, inv, bv.x);
  float o1 = fmaf(a1, inv, bv.y);
  float o2 = fmaf(a2, inv, bv.z);
  float o3 = fmaf(a3, inv, bv.w);
  if (RELU) {
    o0 = fmaxf(o0, 0.f); o1 = fmaxf(o1, 0.f);
    o2 = fmaxf(o2, 0.f); o3 = fmaxf(o3, 0.f);
  }
  if constexpr (std::is_same<OT, float>::value) {
    *(float4*)&out[(size_t)n * 128 + c4 * 4] = make_float4(o0, o1, o2, o3);
  } else {
    uint2 pk;
    pk.x = (uint)f2bf(o0) | ((uint)f2bf(o1) << 16);
    pk.y = (uint)f2bf(o2) | ((uint)f2bf(o3) << 16);
    *(uint2*)&((ushort*)out)[(size_t)n * 128 + c4 * 4] = pk;
  }
}

// ---------------- launch ----------------

extern "C" void kernel_launch(void* const* d_in, const int* in_sizes, int n_in,
                              void* d_out, int out_size, void* d_ws, size_t ws_size,
                              hipStream_t stream) {
  const float* x   = (const float*)d_in[0];
  const int*   ei  = (const int*)d_in[1];
  const float* W0  = (const float*)d_in[2];
  const float* as0 = (const float*)d_in[3];
  const float* ad0 = (const float*)d_in[4];
  const float* b0  = (const float*)d_in[5];
  const float* W1  = (const float*)d_in[6];
  const float* as1 = (const float*)d_in[7];
  const float* ad1 = (const float*)d_in[8];
  const float* b1  = (const float*)d_in[9];

  const int N = in_sizes[0] / 256;   // 100000
  const int E = in_sizes[1] / 2;     // 800000
  const int* src = ei;
  const int* dst = ei + E;

  char* ws = (char*)d_ws;
  size_t off = 0;
  auto alloc = [&](size_t bytes) -> void* {
    void* p = ws + off;
    off += (bytes + 255) & ~(size_t)255;
    return p;
  };
  ushort* xp    = (ushort*)alloc((size_t)N * 128 * 2);
  ushort* hbuf  = (ushort*)alloc((size_t)N * 128 * 2);
  float* a_src  = (float*)alloc((size_t)N * 4 * 4);
  float* a_dst  = (float*)alloc((size_t)N * 4 * 4);
  float* wbuf   = (float*)alloc((size_t)E * 4 * 4);
  int*   counts = (int*)alloc((size_t)N * 4);
  int*   indptr = (int*)alloc((size_t)N * 4);
  int*   cursor = (int*)alloc((size_t)N * 4);
  int*   ssort  = (int*)alloc((size_t)E * 4);
  int*   dsort  = (int*)alloc((size_t)E * 4);
  int*   bsums  = (int*)alloc(256 * 4);
  ushort* Wb0   = (ushort*)alloc((size_t)128 * 256 * 2);
  ushort* Wb1   = (ushort*)alloc((size_t)128 * 128 * 2);

  // ---- init (zero counts + W conversion) + CSR build (by dst) ----
  int n4 = N / 4;
  int eb = (E + 255) / 256;
  int nb = (N + 2047) / 2048;
  k_init<<<128, 256, 0, stream>>>(W0, W1, Wb0, Wb1, (int4*)counts, n4);
  k_count<<<eb, 256, 0, stream>>>(dst, counts, E);
  k_scan1<<<nb, 256, 0, stream>>>(counts, indptr, bsums, N);
  k_scan23<<<nb, 256, 0, stream>>>(indptr, cursor, bsums, N);
  k_fill<<<eb, 256, 0, stream>>>(src, dst, cursor, ssort, dsort, E);

  int gb = (N + 63) / 64;
  int gb8 = (N + 7) / 8;

  // ---- layer 0 ----
  k_gemm_lds<float, 256><<<gb, 256, 0, stream>>>(x, Wb0, as0, ad0, xp,
                                                 a_src, a_dst, N);
  k_wedge<<<eb, 256, 0, stream>>>(ssort, dsort, a_src, a_dst, wbuf, E);
  k_agg<true, ushort><<<gb8, 256, 0, stream>>>(xp, wbuf, ssort, indptr,
                                               counts, b0, hbuf, N);

  // ---- layer 1 ----
  k_gemm_lds<ushort, 128><<<gb, 256, 0, stream>>>(hbuf, Wb1, as1, ad1, xp,
                                                  a_src, a_dst, N);
  k_wedge<<<eb, 256, 0, stream>>>(ssort, dsort, a_src, a_dst, wbuf, E);
  k_agg<false, float><<<gb8, 256, 0, stream>>>(xp, wbuf, ssort, indptr,
                                               counts, b1, (float*)d_out, N);
}

// Round 17
// 249.530 us; speedup vs baseline: 1.0351x; 1.0351x over previous
//
#include <hip/hip_runtime.h>
#include <hip/hip_bf16.h>
#include <cstdint>
#include <cstddef>
#include <type_traits>

#define SLOPE 0.2f

typedef __attribute__((ext_vector_type(8))) short short8v;
typedef __attribute__((ext_vector_type(4))) float float4v;

__device__ inline ushort f2bf(float f) {
  uint u = __float_as_uint(f);
  uint r = (u + 0x7FFFu + ((u >> 16) & 1u)) >> 16;
  return (ushort)r;
}
__device__ inline float bf2f(ushort u) {
  return __uint_as_float(((uint)u) << 16);
}
__device__ inline float bflo(uint u) { return __uint_as_float(u << 16); }
__device__ inline float bfhi(uint u) { return __uint_as_float(u & 0xffff0000u); }

__device__ inline short8v pack8(float4 a, float4 b) {
  uint4 r;
  r.x = (uint)f2bf(a.x) | ((uint)f2bf(a.y) << 16);
  r.y = (uint)f2bf(a.z) | ((uint)f2bf(a.w) << 16);
  r.z = (uint)f2bf(b.x) | ((uint)f2bf(b.y) << 16);
  r.w = (uint)f2bf(b.z) | ((uint)f2bf(b.w) << 16);
  return __builtin_bit_cast(short8v, r);
}
__device__ inline float lrelu(float v) { return (v > 0.f) ? v : SLOPE * v; }

// ---------------- init: zero counts + convert W0/W1 to bf16 (one kernel) ----

__global__ void k_init(const float* __restrict__ W0, const float* __restrict__ W1,
                       ushort* __restrict__ Wb0, ushort* __restrict__ Wb1,
                       int4* __restrict__ counts4, int n4) {
  int i = blockIdx.x * 256 + threadIdx.x;
  if (i < 128 * 256) Wb0[i] = f2bf(W0[i]);
  if (i < 128 * 128) Wb1[i] = f2bf(W1[i]);
  if (i < n4) counts4[i] = make_int4(0, 0, 0, 0);
}

// ---------------- CSR build ----------------

__global__ void k_count(const int* __restrict__ dst, int* __restrict__ counts, int E) {
  int e = blockIdx.x * 256 + threadIdx.x;
  if (e < E) atomicAdd(&counts[dst[e]], 1);
}

__global__ void k_scan1(const int* __restrict__ counts, int* __restrict__ excl,
                        int* __restrict__ bsums, int N) {
  __shared__ int lds[256];
  int tid = threadIdx.x;
  int base = blockIdx.x * 2048 + tid * 8;
  int v[8];
  int ts = 0;
#pragma unroll
  for (int i = 0; i < 8; i++) {
    int idx = base + i;
    int t = (idx < N) ? counts[idx] : 0;
    v[i] = ts;
    ts += t;
  }
  lds[tid] = ts;
  __syncthreads();
  for (int off = 1; off < 256; off <<= 1) {
    int t = (tid >= off) ? lds[tid - off] : 0;
    __syncthreads();
    lds[tid] += t;
    __syncthreads();
  }
  int texcl = (tid > 0) ? lds[tid - 1] : 0;
#pragma unroll
  for (int i = 0; i < 8; i++) {
    int idx = base + i;
    if (idx < N) excl[idx] = texcl + v[i];
  }
  if (tid == 255) bsums[blockIdx.x] = lds[255];
}

// scan finish: add block offsets; write cursor and packed (start,deg) segs
__global__ void k_scan23(const int* __restrict__ excl, const int* __restrict__ counts,
                         int* __restrict__ cursor, int2* __restrict__ seg,
                         const int* __restrict__ bsums, int N) {
  int off = 0;
  for (int j = 0; j < blockIdx.x; j++) off += bsums[j];
  int tid = threadIdx.x;
  int base = blockIdx.x * 2048 + tid * 8;
#pragma unroll
  for (int i = 0; i < 8; i++) {
    int idx = base + i;
    if (idx < N) {
      int val = excl[idx] + off;
      cursor[idx] = val;
      seg[idx] = make_int2(val, counts[idx]);
    }
  }
}

__global__ void k_fill(const int* __restrict__ src, const int* __restrict__ dst,
                       int* __restrict__ cursor, int* __restrict__ src_sorted, int E) {
  int e = blockIdx.x * 256 + threadIdx.x;
  if (e < E) {
    int d = dst[e];
    int pos = atomicAdd(&cursor[d], 1);
    src_sorted[pos] = src[e];
  }
}

// ---------------- MFMA GEMM: 64-row tiles, W in LDS, batched A-loads --------

template <typename AT, int K>
__global__ __launch_bounds__(256, 4) void k_gemm_lds(
    const AT* __restrict__ A, const ushort* __restrict__ Wb,
    const float* __restrict__ att_src, const float* __restrict__ att_dst,
    ushort* __restrict__ C, float* __restrict__ a_src, float* __restrict__ a_dst,
    int M) {
  constexpr int KH = 128;              // staged K chunk
  constexpr int LDW = KH + 8;
  __shared__ ushort Ws[128 * LDW];     // 34816 B
  const int tid = threadIdx.x;
  const int wave = tid >> 6, lane = tid & 63;
  const int fr = lane & 15, fq = lane >> 4;
  const int bm = blockIdx.x * 64;
  const int r0 = bm + wave * 16 + fr;
  const int rc0 = min(r0, M - 1);
  const AT* arow = A + (size_t)rc0 * K + fq * 8;

  const int sr = tid >> 1;                  // staging row 0..127
  const int scb = (tid & 1) * (KH / 2);     // staging col base {0,64}
  const ushort* wrow = Wb + (size_t)sr * K + scb;
  ushort* drow = &Ws[sr * LDW + scb];

  // stage W half 0 (ds_writes issued; barrier comes after A-load issue)
#pragma unroll
  for (int i = 0; i < KH / 16; i++)
    *(uint4*)(drow + i * 8) = *(const uint4*)(wrow + i * 8);

  float4v acc[8] = {};

  if constexpr (std::is_same<AT, float>::value) {
    // ---- fp32 A (layer 0, K=256) ----
    float4 a0[4][2];
#pragma unroll
    for (int s = 0; s < 4; s++) {              // 8 loads in flight
      const float* p = arow + s * 32;
      a0[s][0] = *(const float4*)p;
      a0[s][1] = *(const float4*)(p + 4);
    }
    __syncthreads();                           // W0 staged; A0 still flying
#pragma unroll
    for (int s = 0; s < 4; s++) {
      short8v af = pack8(a0[s][0], a0[s][1]);
#pragma unroll
      for (int t = 0; t < 8; t++) {
        short8v bfr = *(const short8v*)&Ws[(t * 16 + fr) * LDW + s * 32 + fq * 8];
        acc[t] = __builtin_amdgcn_mfma_f32_16x16x32_bf16(af, bfr, acc[t], 0, 0, 0);
      }
    }
    // half 1: issue A loads BEFORE the restage barriers
    float4 a1[4][2];
#pragma unroll
    for (int s = 0; s < 4; s++) {
      const float* p = arow + KH + s * 32;
      a1[s][0] = *(const float4*)p;
      a1[s][1] = *(const float4*)(p + 4);
    }
    __syncthreads();                           // all waves done reading W0
#pragma unroll
    for (int i = 0; i < KH / 16; i++)
      *(uint4*)(drow + i * 8) = *(const uint4*)(wrow + KH + i * 8);
    __syncthreads();                           // W1 staged; A1 long in flight
#pragma unroll
    for (int s = 0; s < 4; s++) {
      short8v af = pack8(a1[s][0], a1[s][1]);
#pragma unroll
      for (int t = 0; t < 8; t++) {
        short8v bfr = *(const short8v*)&Ws[(t * 16 + fr) * LDW + s * 32 + fq * 8];
        acc[t] = __builtin_amdgcn_mfma_f32_16x16x32_bf16(af, bfr, acc[t], 0, 0, 0);
      }
    }
  } else {
    // ---- bf16 A (layer 1, K=128) ----
    short8v a0[4];
#pragma unroll
    for (int s = 0; s < 4; s++)                // 4 loads in flight
      a0[s] = *(const short8v*)(arow + s * 32);
    __syncthreads();
#pragma unroll
    for (int s = 0; s < 4; s++) {
#pragma unroll
      for (int t = 0; t < 8; t++) {
        short8v bfr = *(const short8v*)&Ws[(t * 16 + fr) * LDW + s * 32 + fq * 8];
        acc[t] = __builtin_amdgcn_mfma_f32_16x16x32_bf16(a0[s], bfr, acc[t], 0, 0, 0);
      }
    }
  }

  // att coefficients for this lane's columns (t*16+fr)
  float asc[8], adc[8];
#pragma unroll
  for (int t = 0; t < 8; t++) {
    asc[t] = att_src[t * 16 + fr];
    adc[t] = att_dst[t * 16 + fr];
  }

#pragma unroll
  for (int j = 0; j < 4; j++) {
    int row = bm + wave * 16 + fq * 4 + j;
    bool ok = row < M;
    if (ok) {
#pragma unroll
      for (int t = 0; t < 8; t++)
        C[(size_t)row * 128 + t * 16 + fr] = f2bf(acc[t][j]);
    }
    float ps[4], pd[4];
#pragma unroll
    for (int h = 0; h < 4; h++) {
      ps[h] = acc[2 * h][j] * asc[2 * h] + acc[2 * h + 1][j] * asc[2 * h + 1];
      pd[h] = acc[2 * h][j] * adc[2 * h] + acc[2 * h + 1][j] * adc[2 * h + 1];
    }
#pragma unroll
    for (int off = 1; off < 16; off <<= 1) {
#pragma unroll
      for (int h = 0; h < 4; h++) {
        ps[h] += __shfl_xor(ps[h], off);
        pd[h] += __shfl_xor(pd[h], off);
      }
    }
    if (ok && fr == 0) {
      *(float4*)&a_src[(size_t)row * 4] = make_float4(ps[0], ps[1], ps[2], ps[3]);
      *(float4*)&a_dst[(size_t)row * 4] = make_float4(pd[0], pd[1], pd[2], pd[3]);
    }
  }
}

// ---------------- single-pass aggregation: 32 thr/node, unroll x4 ----------
// The R12-measured local optimum (250.7 us config). No max-subtraction
// (logits bounded; exp ratio identical). seg = packed (start, deg).

template <bool RELU, typename OT>
__global__ __launch_bounds__(256) void k_agg(const ushort* __restrict__ xp,
                                             const float* __restrict__ a_src,
                                             const float* __restrict__ a_dst,
                                             const int* __restrict__ src_sorted,
                                             const int2* __restrict__ seg,
                                             const float* __restrict__ bias,
                                             OT* __restrict__ out, int N) {
  int tid = threadIdx.x;
  int n = blockIdx.x * 8 + (tid >> 5);
  if (n >= N) return;
  int c4 = tid & 31;          // channel group: channels 4*c4 .. 4*c4+3
  int h = c4 >> 3;
  int2 sg = seg[n];
  int start = sg.x, deg = sg.y;
  const int* sp = src_sorted + start;
  const ushort* xpc = xp + c4 * 4;
  const float* asrc_h = a_src + h;
  float ad = a_dst[(size_t)n * 4 + h];

  float a0 = 0.f, a1 = 0.f, a2 = 0.f, a3 = 0.f, s = 0.f;
  int i = 0;
  for (; i + 4 <= deg; i += 4) {
    int s0 = sp[i], s1 = sp[i + 1], s2 = sp[i + 2], s3 = sp[i + 3];
    float e0 = asrc_h[(size_t)s0 * 4], e1 = asrc_h[(size_t)s1 * 4];
    float e2 = asrc_h[(size_t)s2 * 4], e3 = asrc_h[(size_t)s3 * 4];
    uint2 v0 = *(const uint2*)(xpc + (size_t)s0 * 128);
    uint2 v1 = *(const uint2*)(xpc + (size_t)s1 * 128);
    uint2 v2 = *(const uint2*)(xpc + (size_t)s2 * 128);
    uint2 v3 = *(const uint2*)(xpc + (size_t)s3 * 128);
    float x0 = __expf(lrelu(e0 + ad)), x1 = __expf(lrelu(e1 + ad));
    float x2 = __expf(lrelu(e2 + ad)), x3 = __expf(lrelu(e3 + ad));
    s += x0 + x1 + x2 + x3;
    a0 = fmaf(bflo(v0.x), x0, a0); a1 = fmaf(bfhi(v0.x), x0, a1);
    a2 = fmaf(bflo(v0.y), x0, a2); a3 = fmaf(bfhi(v0.y), x0, a3);
    a0 = fmaf(bflo(v1.x), x1, a0); a1 = fmaf(bfhi(v1.x), x1, a1);
    a2 = fmaf(bflo(v1.y), x1, a2); a3 = fmaf(bfhi(v1.y), x1, a3);
    a0 = fmaf(bflo(v2.x), x2, a0); a1 = fmaf(bfhi(v2.x), x2, a1);
    a2 = fmaf(bflo(v2.y), x2, a2); a3 = fmaf(bfhi(v2.y), x2, a3);
    a0 = fmaf(bflo(v3.x), x3, a0); a1 = fmaf(bfhi(v3.x), x3, a1);
    a2 = fmaf(bflo(v3.y), x3, a2); a3 = fmaf(bfhi(v3.y), x3, a3);
  }
  for (; i < deg; i++) {
    int s0 = sp[i];
    float x0 = __expf(lrelu(asrc_h[(size_t)s0 * 4] + ad));
    uint2 v0 = *(const uint2*)(xpc + (size_t)s0 * 128);
    s += x0;
    a0 = fmaf(bflo(v0.x), x0, a0); a1 = fmaf(bfhi(v0.x), x0, a1);
    a2 = fmaf(bflo(v0.y), x0, a2); a3 = fmaf(bfhi(v0.y), x0, a3);
  }

  float inv = 1.f / (s + 1e-16f);
  float4 bv = *(const float4*)&bias[c4 * 4];
  float o0 = fmaf(a0, inv, bv.x);
  float o1 = fmaf(a1, inv, bv.y);
  float o2 = fmaf(a2, inv, bv.z);
  float o3 = fmaf(a3, inv, bv.w);
  if (RELU) {
    o0 = fmaxf(o0, 0.f); o1 = fmaxf(o1, 0.f);
    o2 = fmaxf(o2, 0.f); o3 = fmaxf(o3, 0.f);
  }
  if constexpr (std::is_same<OT, float>::value) {
    *(float4*)&out[(size_t)n * 128 + c4 * 4] = make_float4(o0, o1, o2, o3);
  } else {
    uint2 pk;
    pk.x = (uint)f2bf(o0) | ((uint)f2bf(o1) << 16);
    pk.y = (uint)f2bf(o2) | ((uint)f2bf(o3) << 16);
    *(uint2*)&((ushort*)out)[(size_t)n * 128 + c4 * 4] = pk;
  }
}

// ---------------- launch ----------------

extern "C" void kernel_launch(void* const* d_in, const int* in_sizes, int n_in,
                              void* d_out, int out_size, void* d_ws, size_t ws_size,
                              hipStream_t stream) {
  const float* x   = (const float*)d_in[0];
  const int*   ei  = (const int*)d_in[1];
  const float* W0  = (const float*)d_in[2];
  const float* as0 = (const float*)d_in[3];
  const float* ad0 = (const float*)d_in[4];
  const float* b0  = (const float*)d_in[5];
  const float* W1  = (const float*)d_in[6];
  const float* as1 = (const float*)d_in[7];
  const float* ad1 = (const float*)d_in[8];
  const float* b1  = (const float*)d_in[9];

  const int N = in_sizes[0] / 256;   // 100000
  const int E = in_sizes[1] / 2;     // 800000
  const int* src = ei;
  const int* dst = ei + E;

  char* ws = (char*)d_ws;
  size_t off = 0;
  auto alloc = [&](size_t bytes) -> void* {
    void* p = ws + off;
    off += (bytes + 255) & ~(size_t)255;
    return p;
  };
  ushort* xp    = (ushort*)alloc((size_t)N * 128 * 2);
  ushort* hbuf  = (ushort*)alloc((size_t)N * 128 * 2);
  float* a_src  = (float*)alloc((size_t)N * 4 * 4);
  float* a_dst  = (float*)alloc((size_t)N * 4 * 4);
  int*   counts = (int*)alloc((size_t)N * 4);
  int*   excl   = (int*)alloc((size_t)N * 4);
  int*   cursor = (int*)alloc((size_t)N * 4);
  int2*  seg    = (int2*)alloc((size_t)N * 8);
  int*   ssort  = (int*)alloc((size_t)E * 4);
  int*   bsums  = (int*)alloc(256 * 4);
  ushort* Wb0   = (ushort*)alloc((size_t)128 * 256 * 2);
  ushort* Wb1   = (ushort*)alloc((size_t)128 * 128 * 2);

  // ---- init (zero counts + W conversion) + CSR build (by dst) ----
  int n4 = N / 4;
  int eb = (E + 255) / 256;
  int nb = (N + 2047) / 2048;
  k_init<<<128, 256, 0, stream>>>(W0, W1, Wb0, Wb1, (int4*)counts, n4);
  k_count<<<eb, 256, 0, stream>>>(dst, counts, E);
  k_scan1<<<nb, 256, 0, stream>>>(counts, excl, bsums, N);
  k_scan23<<<nb, 256, 0, stream>>>(excl, counts, cursor, seg, bsums, N);
  k_fill<<<eb, 256, 0, stream>>>(src, dst, cursor, ssort, E);

  int gb = (N + 63) / 64;
  int gb8 = (N + 7) / 8;

  // ---- layer 0 ----
  k_gemm_lds<float, 256><<<gb, 256, 0, stream>>>(x, Wb0, as0, ad0, xp,
                                                 a_src, a_dst, N);
  k_agg<true, ushort><<<gb8, 256, 0, stream>>>(xp, a_src, a_dst, ssort, seg,
                                               b0, hbuf, N);

  // ---- layer 1 ----
  k_gemm_lds<ushort, 128><<<gb, 256, 0, stream>>>(hbuf, Wb1, as1, ad1, xp,
                                                  a_src, a_dst, N);
  k_agg<false, float><<<gb8, 256, 0, stream>>>(xp, a_src, a_dst, ssort, seg,
                                               b1, (float*)d_out, N);
}